// Round 3
// baseline (958.957 us; speedup 1.0000x reference)
//
#include <hip/hip_runtime.h>

// Correctness-isolation build: pure fp32 everywhere, no MFMA, no bf16.
// 3-layer tanh RNN. B=32, T=64, D_IN=10000, H=200, N_CLASSES=2.
// Pipeline: [zero P] gemm0 -> rec0 -> [zero P] gemm1 -> rec1 ->
//           [zero P] gemm2 -> rec2 -> fc

#define HDIM 200

// C[m][n] += sum_{k in [kb, kb+kchunk)} A[m][k] * B[n][k]
// Block: 256 threads, BM=128 rows. Thread tid<200 owns column n=tid,
// accumulates 128 rows in registers; A k-slab staged in LDS (broadcast reads).
// C must be pre-zeroed; k-splits combine via fp32 atomicAdd.
__global__ __launch_bounds__(256, 1)
void gemm_nt_f32(const float* __restrict__ A, int lda,
                 const float* __restrict__ B, int ldb,
                 float* __restrict__ C, int kchunk)
{
    __shared__ float Xs[128][8];
    const int tid = threadIdx.x;
    const int m0  = blockIdx.x * 128;
    const int kb  = blockIdx.y * kchunk;

    float acc[128];
#pragma unroll
    for (int m = 0; m < 128; ++m) acc[m] = 0.f;

    const int srow  = tid >> 1;        // 0..127
    const int shalf = (tid & 1) * 4;   // 0 or 4

    for (int kc = kb; kc < kb + kchunk; kc += 8) {
        // stage A[m0+srow][kc+shalf .. +3]  (all 256 threads participate)
        float4 xv = *(const float4*)(A + (size_t)(m0 + srow) * lda + kc + shalf);
        *(float4*)&Xs[srow][shalf] = xv;
        __syncthreads();

        if (tid < HDIM) {
            const float* wp = B + (size_t)tid * ldb + kc;
            float4 w0 = *(const float4*)wp;
            float4 w1 = *(const float4*)(wp + 4);
#pragma unroll
            for (int m = 0; m < 128; ++m) {
                float4 x0 = *(const float4*)&Xs[m][0];   // wave-broadcast
                float4 x1 = *(const float4*)&Xs[m][4];
                acc[m] += x0.x * w0.x + x0.y * w0.y + x0.z * w0.z + x0.w * w0.w
                        + x1.x * w1.x + x1.y * w1.y + x1.z * w1.z + x1.w * w1.w;
            }
        }
        __syncthreads();
    }

    if (tid < HDIM) {
#pragma unroll
        for (int m = 0; m < 128; ++m)
            atomicAdd(&C[(size_t)(m0 + m) * HDIM + tid], acc[m]);
    }
}

// One workgroup per batch element. W_hh row j in thread j's VGPRs.
// h double-buffered in LDS; 1 barrier/step. Pure fp32.
__global__ __launch_bounds__(256, 1)
void rnn_rec(const float* __restrict__ pre,   // [32][64][200] (GEMM only)
             const float* __restrict__ Whh,   // [200][200]
             const float* __restrict__ bih,
             const float* __restrict__ bhh,
             float* __restrict__ Hout)        // [32][64][200]
{
    const int b   = blockIdx.x;
    const int tid = threadIdx.x;

    __shared__ float h[2][200];
    __shared__ float bias[200];

    float w[200];
    if (tid < HDIM) {
        const float* wr = Whh + (size_t)tid * HDIM;
#pragma unroll
        for (int i = 0; i < 50; ++i) {
            float4 v = *(const float4*)(wr + i * 4);
            w[i * 4 + 0] = v.x; w[i * 4 + 1] = v.y;
            w[i * 4 + 2] = v.z; w[i * 4 + 3] = v.w;
        }
        bias[tid] = bih[tid] + bhh[tid];
        h[0][tid] = 0.f;
    }
    __syncthreads();

    const float* preb = pre + (size_t)b * 64 * HDIM;

    for (int t = 0; t < 64; ++t) {
        float p = (tid < HDIM) ? preb[t * HDIM + tid] : 0.f;
        const float* hc = h[t & 1];
        float acc = 0.f;
#pragma unroll
        for (int k4 = 0; k4 < 50; ++k4) {
            float4 hv = *(const float4*)&hc[k4 * 4];
            acc += w[k4 * 4 + 0] * hv.x;
            acc += w[k4 * 4 + 1] * hv.y;
            acc += w[k4 * 4 + 2] * hv.z;
            acc += w[k4 * 4 + 3] * hv.w;
        }
        if (tid < HDIM) {
            float v = tanhf(acc + p + bias[tid]);
            h[(t + 1) & 1][tid] = v;
            Hout[((size_t)b * 64 + t) * HDIM + tid] = v;
        }
        __syncthreads();
    }
}

// Trivially-correct FC: one thread per logit, serial 200-length dot.
__global__ void fc_head(const float* __restrict__ Hlast_base, // [32][64][200]
                        const float* __restrict__ fcw,        // [2][200]
                        const float* __restrict__ fcb,        // [2]
                        float* __restrict__ out)              // [32][2]
{
    const int i = threadIdx.x;   // 0..63
    if (i >= 64) return;
    const int b   = i >> 1;
    const int cls = i & 1;
    const float* hp = Hlast_base + ((size_t)b * 64 + 63) * HDIM;
    const float* fw = fcw + cls * HDIM;
    float s = fcb[cls];
    for (int j = 0; j < HDIM; ++j) s += hp[j] * fw[j];
    out[b * 2 + cls] = s;
}

extern "C" void kernel_launch(void* const* d_in, const int* in_sizes, int n_in,
                              void* d_out, int out_size, void* d_ws, size_t ws_size,
                              hipStream_t stream) {
    const float* x     = (const float*)d_in[0];
    const float* W_ih0 = (const float*)d_in[1];
    const float* W_hh0 = (const float*)d_in[2];
    const float* b_ih0 = (const float*)d_in[3];
    const float* b_hh0 = (const float*)d_in[4];
    const float* W_ih1 = (const float*)d_in[5];
    const float* W_hh1 = (const float*)d_in[6];
    const float* b_ih1 = (const float*)d_in[7];
    const float* b_hh1 = (const float*)d_in[8];
    const float* W_ih2 = (const float*)d_in[9];
    const float* W_hh2 = (const float*)d_in[10];
    const float* b_ih2 = (const float*)d_in[11];
    const float* b_hh2 = (const float*)d_in[12];
    const float* fc_w  = (const float*)d_in[13];
    const float* fc_b  = (const float*)d_in[14];
    float* out = (float*)d_out;

    const size_t PRE_ELEMS = (size_t)2048 * HDIM;   // 409600 floats
    float* P     = (float*)d_ws;
    float* Hbuf  = P + PRE_ELEMS;
    float* Hbuf2 = Hbuf + PRE_ELEMS;

    // ---- layer 0: P = x @ W_ih0^T  (M=2048, K=10000, 25-way K-split) ----
    hipMemsetAsync(P, 0, PRE_ELEMS * sizeof(float), stream);
    gemm_nt_f32<<<dim3(16, 25), 256, 0, stream>>>(x, 10000, W_ih0, 10000, P, 400);
    rnn_rec<<<32, 256, 0, stream>>>(P, W_hh0, b_ih0, b_hh0, Hbuf);

    // ---- layer 1: P = H0 @ W_ih1^T  (K=200) ----
    hipMemsetAsync(P, 0, PRE_ELEMS * sizeof(float), stream);
    gemm_nt_f32<<<dim3(16, 1), 256, 0, stream>>>(Hbuf, HDIM, W_ih1, HDIM, P, HDIM);
    rnn_rec<<<32, 256, 0, stream>>>(P, W_hh1, b_ih1, b_hh1, Hbuf2);

    // ---- layer 2: P = H1 @ W_ih2^T  (K=200) ----
    hipMemsetAsync(P, 0, PRE_ELEMS * sizeof(float), stream);
    gemm_nt_f32<<<dim3(16, 1), 256, 0, stream>>>(Hbuf2, HDIM, W_ih2, HDIM, P, HDIM);
    rnn_rec<<<32, 256, 0, stream>>>(P, W_hh2, b_ih2, b_hh2, Hbuf);

    // ---- FC head ----
    fc_head<<<1, 64, 0, stream>>>(Hbuf, fc_w, fc_b, out);
}

// Round 4
// 502.742 us; speedup vs baseline: 1.9075x; 1.9075x over previous
//
#include <hip/hip_runtime.h>
#include <hip/hip_bf16.h>

// 3-layer tanh RNN. B=32, T=64, D_IN=10000, H=200, N_CLASSES=2.
// GEMMs: split-bf16 MFMA (v = hi+lo; A*B ~= Ah*Bh + Ah*Bl + Al*Bh -> ~fp32).
// LDS_K=56: row stride 112B keeps every bf16x8 (16B) access 16B-aligned
// (LDS_K=40 in R1/R2 put odd rows at 8 mod 16 -> misaligned ds_*_b128 = the bug)
// and gives 2-way bank aliasing on fragment reads (free per m136).
// rec + fc are the R3-proven fp32 kernels, unchanged.

typedef __bf16  bf16x8 __attribute__((ext_vector_type(8)));
typedef float   f32x4  __attribute__((ext_vector_type(4)));

#define HDIM 200
#define BM 128
#define BN 208      // 13 * 16 (N=200 padded)
#define NT 13
#define BK 32
#define LDS_K 56    // 32 + 24 pad: 112B row stride, 16B-aligned everywhere

__device__ __forceinline__ void split_bf16(const float* v, bf16x8* hi, bf16x8* lo) {
#pragma unroll
    for (int i = 0; i < 8; ++i) {
        __bf16 h = (__bf16)v[i];
        (*hi)[i] = h;
        (*lo)[i] = (__bf16)(v[i] - (float)h);
    }
}

// C[m][n] (+)= sum_k A[m][k] * B[n][k]   (NT-GEMM; B row-major [n][k])
// accumulate=1: atomicAdd into pre-zeroed C (multi-k-block). 0: plain store.
__global__ __launch_bounds__(512, 1)
void gemm_nt_bf16c(const float* __restrict__ A, int lda,
                   const float* __restrict__ B, int ldb,
                   float* __restrict__ C, int Ncols,
                   int K, int ksteps, int accumulate)
{
    __shared__ alignas(16) __bf16 Ash[BM * LDS_K];
    __shared__ alignas(16) __bf16 Asl[BM * LDS_K];
    __shared__ alignas(16) __bf16 Bsh[BN * LDS_K];
    __shared__ alignas(16) __bf16 Bsl[BN * LDS_K];

    const int tid   = threadIdx.x;
    const int m0    = blockIdx.x * BM;
    const int kbase = blockIdx.y * (ksteps * BK);
    const int wv    = tid >> 6;
    const int lane  = tid & 63;
    const int row16 = lane & 15;
    const int kg    = lane >> 4;      // 0..3

    f32x4 acc[NT];
#pragma unroll
    for (int i = 0; i < NT; ++i) acc[i] = (f32x4)0.f;

    const int a_row = tid >> 2;           // 0..127
    const int a_c8  = (tid & 3) * 8;      // 0,8,16,24

    for (int ks = 0; ks < ksteps; ++ks) {
        const int k0 = kbase + ks * BK;
        // ---- stage A tile (128 x 32) fp32 -> hi/lo bf16 ----
        {
            const int k = k0 + a_c8;
            float v[8];
            if (k < K) {   // K % 8 == 0 so the whole 8-group is valid
                const float* p = A + (size_t)(m0 + a_row) * lda + k;
                float4 x0 = *(const float4*)p;
                float4 x1 = *(const float4*)(p + 4);
                v[0]=x0.x; v[1]=x0.y; v[2]=x0.z; v[3]=x0.w;
                v[4]=x1.x; v[5]=x1.y; v[6]=x1.z; v[7]=x1.w;
            } else {
#pragma unroll
                for (int i = 0; i < 8; ++i) v[i] = 0.f;
            }
            bf16x8 th, tl;
            split_bf16(v, &th, &tl);
            *(bf16x8*)&Ash[a_row * LDS_K + a_c8] = th;
            *(bf16x8*)&Asl[a_row * LDS_K + a_c8] = tl;
        }
        // ---- stage B tile (208 x 32): rows >= Ncols zero-padded ----
        for (int u = tid; u < (BN * 4); u += 512) {
            const int r  = u >> 2;
            const int c8 = (u & 3) * 8;
            const int k  = k0 + c8;
            float v[8];
            if (r < Ncols && k < K) {
                const float* p = B + (size_t)r * ldb + k;
                float4 x0 = *(const float4*)p;
                float4 x1 = *(const float4*)(p + 4);
                v[0]=x0.x; v[1]=x0.y; v[2]=x0.z; v[3]=x0.w;
                v[4]=x1.x; v[5]=x1.y; v[6]=x1.z; v[7]=x1.w;
            } else {
#pragma unroll
                for (int i = 0; i < 8; ++i) v[i] = 0.f;
            }
            bf16x8 th, tl;
            split_bf16(v, &th, &tl);
            *(bf16x8*)&Bsh[r * LDS_K + c8] = th;
            *(bf16x8*)&Bsl[r * LDS_K + c8] = tl;
        }
        __syncthreads();

        // ---- MFMA: wave wv owns rows [wv*16, wv*16+16) x all 13 N-tiles ----
        bf16x8 ah = *(const bf16x8*)&Ash[(wv * 16 + row16) * LDS_K + kg * 8];
        bf16x8 al = *(const bf16x8*)&Asl[(wv * 16 + row16) * LDS_K + kg * 8];
#pragma unroll
        for (int nt = 0; nt < NT; ++nt) {
            bf16x8 bh = *(const bf16x8*)&Bsh[(nt * 16 + row16) * LDS_K + kg * 8];
            bf16x8 bl = *(const bf16x8*)&Bsl[(nt * 16 + row16) * LDS_K + kg * 8];
            acc[nt] = __builtin_amdgcn_mfma_f32_16x16x32_bf16(al, bh, acc[nt], 0, 0, 0);
            acc[nt] = __builtin_amdgcn_mfma_f32_16x16x32_bf16(ah, bl, acc[nt], 0, 0, 0);
            acc[nt] = __builtin_amdgcn_mfma_f32_16x16x32_bf16(ah, bh, acc[nt], 0, 0, 0);
        }
        __syncthreads();
    }

    // ---- epilogue: C/D layout col=lane&15, row=(lane>>4)*4+reg ----
    const int mrow = m0 + wv * 16 + kg * 4;
#pragma unroll
    for (int nt = 0; nt < NT; ++nt) {
        const int n = nt * 16 + row16;
        if (n < Ncols) {
            if (accumulate) {
#pragma unroll
                for (int r = 0; r < 4; ++r)
                    atomicAdd(&C[(size_t)(mrow + r) * Ncols + n], acc[nt][r]);
            } else {
#pragma unroll
                for (int r = 0; r < 4; ++r)
                    C[(size_t)(mrow + r) * Ncols + n] = acc[nt][r];
            }
        }
    }
}

// One workgroup per batch element. W_hh row j in thread j's VGPRs.
// h double-buffered in LDS; 1 barrier/step. Pure fp32. (R3-proven.)
__global__ __launch_bounds__(256, 1)
void rnn_rec(const float* __restrict__ pre,   // [32][64][200] (GEMM only)
             const float* __restrict__ Whh,   // [200][200]
             const float* __restrict__ bih,
             const float* __restrict__ bhh,
             float* __restrict__ Hout)        // [32][64][200]
{
    const int b   = blockIdx.x;
    const int tid = threadIdx.x;

    __shared__ float h[2][200];
    __shared__ float bias[200];

    float w[200];
    if (tid < HDIM) {
        const float* wr = Whh + (size_t)tid * HDIM;
#pragma unroll
        for (int i = 0; i < 50; ++i) {
            float4 v = *(const float4*)(wr + i * 4);
            w[i * 4 + 0] = v.x; w[i * 4 + 1] = v.y;
            w[i * 4 + 2] = v.z; w[i * 4 + 3] = v.w;
        }
        bias[tid] = bih[tid] + bhh[tid];
        h[0][tid] = 0.f;
    }
    __syncthreads();

    const float* preb = pre + (size_t)b * 64 * HDIM;

    for (int t = 0; t < 64; ++t) {
        float p = (tid < HDIM) ? preb[t * HDIM + tid] : 0.f;
        const float* hc = h[t & 1];
        float acc = 0.f;
#pragma unroll
        for (int k4 = 0; k4 < 50; ++k4) {
            float4 hv = *(const float4*)&hc[k4 * 4];
            acc += w[k4 * 4 + 0] * hv.x;
            acc += w[k4 * 4 + 1] * hv.y;
            acc += w[k4 * 4 + 2] * hv.z;
            acc += w[k4 * 4 + 3] * hv.w;
        }
        if (tid < HDIM) {
            float v = tanhf(acc + p + bias[tid]);
            h[(t + 1) & 1][tid] = v;
            Hout[((size_t)b * 64 + t) * HDIM + tid] = v;
        }
        __syncthreads();
    }
}

// Trivially-correct FC: one thread per logit, serial 200-length dot. (R3-proven.)
__global__ void fc_head(const float* __restrict__ Hlast_base, // [32][64][200]
                        const float* __restrict__ fcw,        // [2][200]
                        const float* __restrict__ fcb,        // [2]
                        float* __restrict__ out)              // [32][2]
{
    const int i = threadIdx.x;   // 0..63
    if (i >= 64) return;
    const int b   = i >> 1;
    const int cls = i & 1;
    const float* hp = Hlast_base + ((size_t)b * 64 + 63) * HDIM;
    const float* fw = fcw + cls * HDIM;
    float s = fcb[cls];
    for (int j = 0; j < HDIM; ++j) s += hp[j] * fw[j];
    out[b * 2 + cls] = s;
}

extern "C" void kernel_launch(void* const* d_in, const int* in_sizes, int n_in,
                              void* d_out, int out_size, void* d_ws, size_t ws_size,
                              hipStream_t stream) {
    const float* x     = (const float*)d_in[0];
    const float* W_ih0 = (const float*)d_in[1];
    const float* W_hh0 = (const float*)d_in[2];
    const float* b_ih0 = (const float*)d_in[3];
    const float* b_hh0 = (const float*)d_in[4];
    const float* W_ih1 = (const float*)d_in[5];
    const float* W_hh1 = (const float*)d_in[6];
    const float* b_ih1 = (const float*)d_in[7];
    const float* b_hh1 = (const float*)d_in[8];
    const float* W_ih2 = (const float*)d_in[9];
    const float* W_hh2 = (const float*)d_in[10];
    const float* b_ih2 = (const float*)d_in[11];
    const float* b_hh2 = (const float*)d_in[12];
    const float* fc_w  = (const float*)d_in[13];
    const float* fc_b  = (const float*)d_in[14];
    float* out = (float*)d_out;

    const size_t PRE_ELEMS = (size_t)2048 * HDIM;   // 409600 floats
    float* P     = (float*)d_ws;
    float* Hbuf  = P + PRE_ELEMS;
    float* Hbuf2 = Hbuf + PRE_ELEMS;

    // ---- layer 0: P = x @ W_ih0^T  (M=2048, K=10000, 16-way K-split) ----
    hipMemsetAsync(P, 0, PRE_ELEMS * sizeof(float), stream);
    gemm_nt_bf16c<<<dim3(16, 16), 512, 0, stream>>>(x, 10000, W_ih0, 10000, P, HDIM, 10000, 20, 1);
    rnn_rec<<<32, 256, 0, stream>>>(P, W_hh0, b_ih0, b_hh0, Hbuf);

    // ---- layer 1: P = H0 @ W_ih1^T  (K=200, single k-block -> plain store) ----
    gemm_nt_bf16c<<<dim3(16, 1), 512, 0, stream>>>(Hbuf, HDIM, W_ih1, HDIM, P, HDIM, HDIM, 7, 0);
    rnn_rec<<<32, 256, 0, stream>>>(P, W_hh1, b_ih1, b_hh1, Hbuf2);

    // ---- layer 2 ----
    gemm_nt_bf16c<<<dim3(16, 1), 512, 0, stream>>>(Hbuf2, HDIM, W_ih2, HDIM, P, HDIM, HDIM, 7, 0);
    rnn_rec<<<32, 256, 0, stream>>>(P, W_hh2, b_ih2, b_hh2, Hbuf);

    // ---- FC head ----
    fc_head<<<1, 64, 0, stream>>>(Hbuf, fc_w, fc_b, out);
}